// Round 7
// baseline (365.557 us; speedup 1.0000x reference)
//
#include <hip/hip_runtime.h>
#include <hip/hip_bf16.h>
#include <math.h>

// B=32, H=64, W=64, C_IN=384, C_HID=128
// conv3x3(pad1)+b1 -> relu -> conv1x1+b2 -> sigmoid, NHWC fp32.
// R7: 32x32x16 MFMA with row-matched M-tiles (the dual-shrink lever):
//   * Block = 32x8 output px (tile 32 wide so one 32x32 MFMA = one px row),
//     N=128, 512 thr (8 waves = 2M x 4N; wave: 4 rows x 32 ch).
//     Per wave per chunk: 36 af ds_read_b128 + 72 mfma_32x32x16
//     (vs R2: 54 + 144 of 16x16x32). Per-CU ledger (R2 measured ~= sum):
//     LDS 10.4K->6.9K cyc, MFMA 11.2K->9.7K cyc per chunk.
//   * Granule swizzle slot=(g+hy+(hx&3))&3 on the 16B ch-granules: the
//     64B px-stride would put 32-lane b128 reads on 16 banks; swizzle
//     restores the 8-slot all-32-bank pattern. Write side computes it
//     from (hy,hx) of px; read side uses hx=ox+lq (exact, no carry).
//   * acc[4] f32x16 = 64 AGPR; ksub-split keeps bf live at 12 regs;
//     staging = R2's proven pipelined 3-item pattern spread over the 6
//     (ox,ksub) sub-phases (R6 lesson: fused load+pack serializes).
//   * Keep: s_setprio around MFMA, plain __syncthreads (R5 null),
//     no B ping-pong (R4 null).

typedef __attribute__((ext_vector_type(8))) unsigned short ushort8;
typedef __attribute__((ext_vector_type(8))) __bf16 bf16x8;
typedef __attribute__((ext_vector_type(16))) float floatx16;

#define HW2 34             // halo width (32+2)
#define BUF 10880          // 340 px * 32 ch elems per chunk buffer

static __device__ __forceinline__ unsigned short f2bf_rne(float f) {
  union { float f; unsigned int u; } x; x.f = f;
  unsigned int u = x.u;
  return (unsigned short)((u + 0x7fffu + ((u >> 16) & 1u)) >> 16);
}

static __device__ __forceinline__ ushort8 pack8(const float* v) {
  ushort8 r;
#pragma unroll
  for (int i = 0; i < 4; ++i) {
    __hip_bfloat162 p = __float22bfloat162_rn(make_float2(v[2 * i], v[2 * i + 1]));
    union { __hip_bfloat162 b; unsigned int u; } c;
    c.b = p;
    r[2 * i] = (unsigned short)(c.u & 0xffffu);
    r[2 * i + 1] = (unsigned short)(c.u >> 16);
  }
  return r;
}

// W1 (3,3,384,128 HWIO fp32) -> bf16 W1b[kk][n][c], kk=o*12+chunk, n=0..127, c=0..31.
__global__ void prep_w1_kernel(const float* __restrict__ W1,
                               unsigned short* __restrict__ W1b) {
  __shared__ unsigned short tile[32 * 128];
  const int kk = blockIdx.x;            // 0..107
  const int o = kk / 12;
  const int chunk = kk - o * 12;
  const float* src = W1 + (o * 384 + chunk * 32) * 128;  // [c][n], n contiguous
  const int t = threadIdx.x;
#pragma unroll
  for (int i = 0; i < 16; ++i) {
    int idx = t + i * 256;              // idx = c*128+n
    int c = idx >> 7;
    int n = idx & 127;
    tile[n * 32 + c] = f2bf_rne(src[idx]);
  }
  __syncthreads();
  unsigned short* dst = W1b + kk * 4096;
#pragma unroll
  for (int i = 0; i < 16; ++i) {
    int idx = t + i * 256;
    dst[idx] = tile[idx];
  }
}

// ---- staging: load 8 ch of halo item JJ into float DST[8] ----
#define SLOADF(DST, JJ, CHOFF)                                               \
  if ((smask >> (JJ)) & 1) {                                                 \
    *(float4*)&DST[0] = *(const float4*)(x + soff[JJ] + (CHOFF));            \
    *(float4*)&DST[4] = *(const float4*)(x + soff[JJ] + (CHOFF) + 4);        \
  } else {                                                                   \
    _Pragma("unroll") for (int e = 0; e < 8; ++e) DST[e] = 0.0f;             \
  }

// ---- staging: pack + write item JJ to its swizzled LDS slot ----
#define SWR(SRC, JJ, WB)                                                     \
  if ((JJ) < 2 || t < 336)                                                   \
    *(ushort8*)&Ah[(WB) + (witem[JJ] << 3)] = pack8(SRC);

__global__ __launch_bounds__(512, 4) void conv_fused_kernel(
    const float* __restrict__ x, const unsigned short* __restrict__ W1b,
    const float* __restrict__ b1, const float* __restrict__ W2,
    const float* __restrict__ b2, float* __restrict__ out) {
  __shared__ alignas(16) unsigned short Ah[2 * BUF];  // 43520 B
  __shared__ float hsum[256 * 4];                     // 4096 B

  const int t = threadIdx.x;
  const int w = t >> 6;          // wave 0..7
  const int wm4 = (w >> 2) << 2; // M half: output rows [wm4, wm4+4)
  const int wn = w & 3;          // N quarter: channels [32*wn, 32*wn+32)
  const int lane = t & 63;
  const int l5 = lane >> 5;
  const int lq = lane & 31;

  const int img = blockIdx.x >> 4;       // 32 images
  const int tid = blockIdx.x & 15;       // 8x2 grid of 32x8 tiles
  const int ty0 = (tid >> 1) << 3;
  const int tx0 = (tid & 1) << 5;

  // ---- staging plan: 1360 items (halo px 0..339 x granule 0..3), 8 ch ----
  // item = t + 512*j, j=0..2 (j=2 active only t<336). LDS slot is the
  // granule-swizzled item: witem = px*4 + ((sub + hy + (hx&3)) & 3).
  int smask = 0;
  int soff[3], witem[3];
#pragma unroll
  for (int j = 0; j < 3; ++j) {
    int item = t + (j << 9);
    int px = item >> 2, sub = item & 3;
    int hy = px / 34;
    int hx = px - hy * 34;
    int iy = ty0 + hy - 1, ix = tx0 + hx - 1;
    int v = (item < 1360) && ((unsigned)iy < 64u) && ((unsigned)ix < 64u);
    smask |= (v << j);
    int iyc = v ? iy : 0, ixc = v ? ix : 0;
    soff[j] = ((((img << 6) + iyc) << 6) + ixc) * 384 + sub * 8;
    witem[j] = (px << 2) | ((sub + hy + (hx & 3)) & 3);
  }

  // B frag lane offset (elems): n = wn*32+lq, k-sub = l5*8 (+ ks*16 scalar)
  const int bofflane = ((wn * 32 + lq) << 5) + (l5 << 3);
  // A frag lane px part (elems)
  const int aL = lq << 5;

  floatx16 acc[4] = {};  // acc[mt]: row wm4+mt, px-x=(r&3)+8(r>>2)+4*l5, n=wn*32+lq

  float sA[8], sB[8];

  // ---- prologue: stage chunk 0 into buf0 ----
  {
    SLOADF(sA, 0, 0)
    SLOADF(sB, 1, 0)
    SWR(sA, 0, 0)
    SLOADF(sA, 2, 0)
    SWR(sB, 1, 0)
    SWR(sA, 2, 0)
  }
  __syncthreads();

  for (int c = 0; c < 12; ++c) {
    const int rb = (c & 1) * BUF;        // read buffer (chunk c)
    const int wbuf = BUF - rb;           // write buffer (chunk c+1)
    const int choff = (c + 1) << 5;
    const bool pf = (c < 11);

#pragma unroll
    for (int ox = 0; ox < 3; ++ox) {
      const int vmx = l5 + ((ox + lq) & 3);   // lane part of granule swizzle
#pragma unroll
      for (int ks = 0; ks < 2; ++ks) {
        const int p = ox * 2 + ks;

        // ---- B frags (3 oy x 16B from L2-resident W1b) ----
        bf16x8 bf[3];
#pragma unroll
        for (int oy = 0; oy < 3; ++oy) {
          bf[oy] = *(const bf16x8*)(W1b + (((oy * 3 + ox) * 12 + c) << 12) +
                                    bofflane + (ks << 4));
        }

        // ---- staging interleave: 1.5-phase load->pack distance ----
        if (pf) {
          if (p == 0) {
            SLOADF(sA, 0, choff)
          } else if (p == 2) {
            SWR(sA, 0, wbuf)
            SLOADF(sB, 1, choff)
          } else if (p == 4) {
            SWR(sB, 1, wbuf)
            SLOADF(sA, 2, choff)
          }
        }

        // ---- tap-shared MFMAs: halo row wm4+hl feeds row mt = hl-oy ----
        __builtin_amdgcn_s_setprio(1);
#pragma unroll
        for (int hl = 0; hl < 6; ++hl) {
          const int gp = (hl + 2 * ks + vmx) & 3;  // swizzled granule slot
          const bf16x8 af = *(const bf16x8*)&Ah[rb +
              (((wm4 + hl) * 34 + ox) << 5) + aL + (gp << 3)];
#pragma unroll
          for (int oy = 0; oy < 3; ++oy) {
            const int mt = hl - oy;
            if (mt >= 0 && mt < 4) {
              acc[mt] = __builtin_amdgcn_mfma_f32_32x32x16_bf16(
                  af, bf[oy], acc[mt], 0, 0, 0);
            }
          }
        }
        __builtin_amdgcn_s_setprio(0);
      }
    }
    if (pf) { SWR(sA, 2, wbuf) }
    __syncthreads();
  }

  // ---- epilogue: bias+relu, conv1x1 reduce over n, sigmoid ----
  const float b1v = b1[wn * 32 + lq];
  const float w2v = W2[wn * 32 + lq];
#pragma unroll
  for (int mt = 0; mt < 4; ++mt) {
#pragma unroll
    for (int r = 0; r < 16; ++r) {
      float v = fmaxf(acc[mt][r] + b1v, 0.0f) * w2v;
      v += __shfl_xor(v, 1);
      v += __shfl_xor(v, 2);
      v += __shfl_xor(v, 4);
      v += __shfl_xor(v, 8);
      v += __shfl_xor(v, 16);
      if (lq == 0) {
        int pxx = (r & 3) + ((r >> 2) << 3) + (l5 << 2);
        int row = wm4 + mt;
        hsum[((row << 5) + pxx) * 4 + wn] = v;
      }
    }
  }
  __syncthreads();
  if (t < 256) {
    float4 p = *(const float4*)&hsum[t * 4];
    float s = p.x + p.y + p.z + p.w + b2[0];
    float sig = 1.0f / (1.0f + expf(-s));
    int row = t >> 5, col = t & 31;
    out[(((img << 6) + ty0 + row) << 6) + tx0 + col] = sig;
  }
}

extern "C" void kernel_launch(void* const* d_in, const int* in_sizes, int n_in,
                              void* d_out, int out_size, void* d_ws, size_t ws_size,
                              hipStream_t stream) {
  const float* x  = (const float*)d_in[0];   // (32,64,64,384)
  const float* W1 = (const float*)d_in[1];   // (3,3,384,128)
  const float* b1 = (const float*)d_in[2];   // (128)
  const float* W2 = (const float*)d_in[3];   // (128)
  const float* b2 = (const float*)d_in[4];   // (1)
  float* out = (float*)d_out;                // (32,64,64,1)
  unsigned short* W1b = (unsigned short*)d_ws;  // 108*4096*2 = 884736 B

  prep_w1_kernel<<<108, 256, 0, stream>>>(W1, W1b);
  conv_fused_kernel<<<512, 512, 0, stream>>>(x, W1b, b1, W2, b2, out);
}